// Round 3
// baseline (105.278 us; speedup 1.0000x reference)
//
#include <hip/hip_runtime.h>
#include <hip/hip_cooperative_groups.h>
#include <math.h>

namespace cg = cooperative_groups;

#define PI_F 3.14159265358979323846f

typedef _Float16 h16x8 __attribute__((ext_vector_type(8)));
typedef float f32x4 __attribute__((ext_vector_type(4)));

// ---------------------------------------------------------------------------
// Register-resident 256-amp simulator helpers (4 amps/lane, 64 lanes/wave).
// Amplitude index: idx = lane*4 + j. Wire w acts on bit b = 7 - w.
// ---------------------------------------------------------------------------

__device__ __forceinline__ void apply_ry_g(float2 a[4], const int b, const int lane,
                                           const float c, const float s) {
    if (b >= 2) {
        const int lb = b - 2;
        const float sg = ((lane >> lb) & 1) ? s : -s;
#pragma unroll
        for (int j = 0; j < 4; ++j) {
            float px = __shfl_xor(a[j].x, 1 << lb, 64);
            float py = __shfl_xor(a[j].y, 1 << lb, 64);
            a[j].x = c * a[j].x + sg * px;
            a[j].y = c * a[j].y + sg * py;
        }
    } else if (b == 1) {
        float2 n0, n1, n2, n3;
        n0.x = c * a[0].x - s * a[2].x; n0.y = c * a[0].y - s * a[2].y;
        n2.x = s * a[0].x + c * a[2].x; n2.y = s * a[0].y + c * a[2].y;
        n1.x = c * a[1].x - s * a[3].x; n1.y = c * a[1].y - s * a[3].y;
        n3.x = s * a[1].x + c * a[3].x; n3.y = s * a[1].y + c * a[3].y;
        a[0] = n0; a[1] = n1; a[2] = n2; a[3] = n3;
    } else {
        float2 n0, n1, n2, n3;
        n0.x = c * a[0].x - s * a[1].x; n0.y = c * a[0].y - s * a[1].y;
        n1.x = s * a[0].x + c * a[1].x; n1.y = s * a[0].y + c * a[1].y;
        n2.x = c * a[2].x - s * a[3].x; n2.y = c * a[2].y - s * a[3].y;
        n3.x = s * a[2].x + c * a[3].x; n3.y = s * a[2].y + c * a[3].y;
        a[0] = n0; a[1] = n1; a[2] = n2; a[3] = n3;
    }
}

__device__ __forceinline__ void apply_rx_g(float2 a[4], const int b, const int lane,
                                           const float c, const float s) {
    if (b >= 2) {
        const int lb = b - 2;
#pragma unroll
        for (int j = 0; j < 4; ++j) {
            float px = __shfl_xor(a[j].x, 1 << lb, 64);
            float py = __shfl_xor(a[j].y, 1 << lb, 64);
            a[j].x = c * a[j].x + s * py;
            a[j].y = c * a[j].y - s * px;
        }
    } else if (b == 1) {
        float2 n0, n1, n2, n3;
        n0.x = c * a[0].x + s * a[2].y; n0.y = c * a[0].y - s * a[2].x;
        n2.x = c * a[2].x + s * a[0].y; n2.y = c * a[2].y - s * a[0].x;
        n1.x = c * a[1].x + s * a[3].y; n1.y = c * a[1].y - s * a[3].x;
        n3.x = c * a[3].x + s * a[1].y; n3.y = c * a[3].y - s * a[1].x;
        a[0] = n0; a[1] = n1; a[2] = n2; a[3] = n3;
    } else {
        float2 n0, n1, n2, n3;
        n0.x = c * a[0].x + s * a[1].y; n0.y = c * a[0].y - s * a[1].x;
        n1.x = c * a[1].x + s * a[0].y; n1.y = c * a[1].y - s * a[0].x;
        n2.x = c * a[2].x + s * a[3].y; n2.y = c * a[2].y - s * a[3].x;
        n3.x = c * a[3].x + s * a[2].y; n3.y = c * a[3].y - s * a[2].x;
        a[0] = n0; a[1] = n1; a[2] = n2; a[3] = n3;
    }
}

__device__ __forceinline__ void apply_cnot_g(float2 a[4], const int cw, const int lane) {
    if (cw <= 4) {
        const int lt = (6 - cw) - 2;
        const int lc = lt + 1;
        const bool ctrl = ((lane >> lc) & 1) != 0;
#pragma unroll
        for (int j = 0; j < 4; ++j) {
            float px = __shfl_xor(a[j].x, 1 << lt, 64);
            float py = __shfl_xor(a[j].y, 1 << lt, 64);
            a[j].x = ctrl ? px : a[j].x;
            a[j].y = ctrl ? py : a[j].y;
        }
    } else if (cw == 5) {
        const bool ctrl = (lane & 1) != 0;
        float2 t;
        t = a[0]; a[0].x = ctrl ? a[2].x : a[0].x; a[0].y = ctrl ? a[2].y : a[0].y;
        a[2].x = ctrl ? t.x : a[2].x; a[2].y = ctrl ? t.y : a[2].y;
        t = a[1]; a[1].x = ctrl ? a[3].x : a[1].x; a[1].y = ctrl ? a[3].y : a[1].y;
        a[3].x = ctrl ? t.x : a[3].x; a[3].y = ctrl ? t.y : a[3].y;
    } else {
        float2 t = a[2]; a[2] = a[3]; a[3] = t;
    }
}

__device__ __forceinline__ unsigned int packh2(float lo, float hi) {
    unsigned short l = __builtin_bit_cast(unsigned short, (_Float16)lo);
    unsigned short h = __builtin_bit_cast(unsigned short, (_Float16)hi);
    return ((unsigned int)h << 16) | (unsigned int)l;
}

__device__ __forceinline__ float2 cmulf(float2 a, float2 b) {
    return make_float2(a.x * b.x - a.y * b.y, a.x * b.y + a.y * b.x);
}

// ---- k-loop helpers: all-compile-time indices (no scratch) ----
__device__ __forceinline__ void loadB4(h16x8 bf[4], const char* ub, const size_t boff[4],
                                       const int kk) {
#pragma unroll
    for (int f = 0; f < 4; ++f)
        bf[f] = *(const h16x8*)(ub + (size_t)kk * 32768 + boff[f]);
}

__device__ __forceinline__ void loadA4(h16x8 av[4], const char* apc, const unsigned int aoff,
                                       const int kk) {
#pragma unroll
    for (int rt = 0; rt < 4; ++rt)
        av[rt] = *(const h16x8*)(apc + kk * 4096 + rt * 1024 + aoff);
}

__device__ __forceinline__ void mfma16(f32x4 acc[4][4], const h16x8 av[4], const h16x8 bf[4]) {
#pragma unroll
    for (int rt = 0; rt < 4; ++rt)
#pragma unroll
        for (int f = 0; f < 4; ++f)
            acc[rt][f] = __builtin_amdgcn_mfma_f32_16x16x32_f16(av[rt], bf[f], acc[rt][f],
                                                                0, 0, 0);
}

// ---------------------------------------------------------------------------
// Fused cooperative kernel.
// Phase 1 (all 256 blocks): build Psi tile (64 rows) into swizzled LDS.
// Phase 1b (blocks 0..31): each of 8 waves sims one U basis column -> Upack.
// grid.sync() with agent-scope fences, then GEMM + FWHT epilogue.
// ---------------------------------------------------------------------------
__global__ __launch_bounds__(512) void fused_kernel(const float* __restrict__ x,
                                                    const float* __restrict__ w,
                                                    unsigned int* __restrict__ up32,
                                                    float* __restrict__ out) {
    __shared__ unsigned short Ap[16 * 64 * 32];   // 64 KB  Apack[kk][row][kap]
    __shared__ float zbuf[8][64][8];              // 16 KB
    __shared__ float wc[48];
    __shared__ float wsn[48];

    const int tid = threadIdx.x;
    const int bid = blockIdx.x;

    if (bid < 32 && tid < 48) {
        float s, c;
        __sincosf(w[tid] * 0.5f, &s, &c);
        wc[tid] = c; wsn[tid] = s;
    }

    // ---------------- phase 1: Psi tile build (all blocks) ----------------
    {
        const int row = tid >> 3;          // 0..63
        const int t8 = tid & 7;            // n bits 7..5
        const int grow = bid * 64 + row;

        const float4* xp = (const float4*)(x + grow * 8);
        float4 xa = xp[0], xb = xp[1];
        float ang[8] = {xa.x, xa.y, xa.z, xa.w, xb.x, xb.y, xb.z, xb.w};

        float2 v0[8], v1[8];
#pragma unroll
        for (int i = 0; i < 8; ++i) {
            float s, c;
            __sincosf(ang[i] * (PI_F * 0.5f), &s, &c);
            v0[i] = make_float2(c * c, -c * s);
            v1[i] = make_float2(s * c, s * s);
        }

        float2 pre = (t8 & 4) ? v1[0] : v0[0];
        pre = cmulf(pre, (t8 & 2) ? v1[1] : v0[1]);
        pre = cmulf(pre, (t8 & 1) ? v1[2] : v0[2]);

        unsigned int* ap32 = (unsigned int*)Ap;
#pragma unroll
        for (int b4 = 0; b4 < 2; ++b4) {
            float2 p3 = cmulf(pre, b4 ? v1[3] : v0[3]);
#pragma unroll
            for (int b3 = 0; b3 < 2; ++b3) {
                float2 p4 = cmulf(p3, b3 ? v1[4] : v0[4]);
#pragma unroll
                for (int b2 = 0; b2 < 2; ++b2) {
                    float2 p5 = cmulf(p4, b2 ? v1[5] : v0[5]);
#pragma unroll
                    for (int b1 = 0; b1 < 2; ++b1) {
                        float2 p6 = cmulf(p5, b1 ? v1[6] : v0[6]);
#pragma unroll
                        for (int b0 = 0; b0 < 2; ++b0) {
                            float2 ps = cmulf(p6, b0 ? v1[7] : v0[7]);
                            const int nlo = (b4 << 4) | (b3 << 3) | (b2 << 2) | (b1 << 1) | b0;
                            const int kk = t8 * 2 + (nlo >> 4);
                            const int kre = 2 * (nlo & 15);
                            const int slot = (kre >> 3) ^ ((row >> 1) & 3);
                            const unsigned int byte =
                                kk * 4096 + row * 64 + slot * 16 + (kre & 7) * 2;
                            ap32[byte >> 2] = packh2(ps.x, ps.y);
                        }
                    }
                }
            }
        }
    }

    // ---------------- phase 1b: U column sim (blocks 0..31) ----------------
    if (bid < 32) {
        __syncthreads();   // wc/wsn ready (uniform branch: blockIdx is uniform)
        const int lane = tid & 63;
        const int n = bid * 8 + (tid >> 6);   // column 0..255

        float2 a[4];
#pragma unroll
        for (int j = 0; j < 4; ++j) {
            a[j].x = (lane * 4 + j == n) ? 1.0f : 0.0f;
            a[j].y = 0.0f;
        }

#pragma unroll
        for (int L = 0; L < 3; ++L) {
#pragma unroll
            for (int q = 0; q < 8; ++q) {
                const int k = 2 * (L * 8 + q);
                const int b = 7 - q;
                apply_rx_g(a, b, lane, wc[k], wsn[k]);
                apply_ry_g(a, b, lane, wc[k + 1], wsn[k + 1]);
            }
#pragma unroll
            for (int cwire = 0; cwire < 7; ++cwire) apply_cnot_g(a, cwire, lane);
        }

        const int kk = n >> 4;
        const int kre = 2 * (n & 15);
#pragma unroll
        for (int j = 0; j < 4; ++j) {
            const int m = lane * 4 + j;
            up32[(kk * 16384 + m * 32 + kre) >> 1] = packh2(a[j].x, -a[j].y);
            up32[(kk * 16384 + (256 + m) * 32 + kre) >> 1] = packh2(a[j].y, a[j].x);
        }
        __threadfence();   // agent-scope release: publish Upack across XCDs
    }

    cg::this_grid().sync();
    __threadfence();       // acquire side: discard any stale cached Upack lines

    // ---------------- phase 2: GEMM ----------------
    const int lane = tid & 63;
    const int wv = tid >> 6;        // 0..7 : re cols [wv*32, wv*32+32)
    const int c15 = lane & 15;
    const int g = lane >> 4;

    const char* ub = (const char*)up32;
    size_t boff[4];
    {
        const int cb0 = wv * 32;
        boff[0] = (size_t)(cb0 + c15) * 64 + g * 16;
        boff[1] = (size_t)(cb0 + 16 + c15) * 64 + g * 16;
        boff[2] = (size_t)(256 + cb0 + c15) * 64 + g * 16;
        boff[3] = (size_t)(256 + cb0 + 16 + c15) * 64 + g * 16;
    }
    const unsigned int aoff = c15 * 64 + ((g ^ ((c15 >> 1) & 3)) * 16);
    const char* apc = (const char*)Ap;

    f32x4 acc[4][4];
#pragma unroll
    for (int rt = 0; rt < 4; ++rt)
#pragma unroll
        for (int f = 0; f < 4; ++f) {
            f32x4 z = {0.f, 0.f, 0.f, 0.f};
            acc[rt][f] = z;
        }

    h16x8 b0[4], b1[4], b2[4], b3[4];
    h16x8 a0[4], a1[4];

    loadB4(b0, ub, boff, 0);
    loadB4(b1, ub, boff, 1);
    loadB4(b2, ub, boff, 2);
    loadB4(b3, ub, boff, 3);
    loadA4(a0, apc, aoff, 0);

    loadA4(a1, apc, aoff, 1);  mfma16(acc, a0, b0);  loadB4(b0, ub, boff, 4);
    loadA4(a0, apc, aoff, 2);  mfma16(acc, a1, b1);  loadB4(b1, ub, boff, 5);
    loadA4(a1, apc, aoff, 3);  mfma16(acc, a0, b2);  loadB4(b2, ub, boff, 6);
    loadA4(a0, apc, aoff, 4);  mfma16(acc, a1, b3);  loadB4(b3, ub, boff, 7);
    loadA4(a1, apc, aoff, 5);  mfma16(acc, a0, b0);  loadB4(b0, ub, boff, 8);
    loadA4(a0, apc, aoff, 6);  mfma16(acc, a1, b1);  loadB4(b1, ub, boff, 9);
    loadA4(a1, apc, aoff, 7);  mfma16(acc, a0, b2);  loadB4(b2, ub, boff, 10);
    loadA4(a0, apc, aoff, 8);  mfma16(acc, a1, b3);  loadB4(b3, ub, boff, 11);
    loadA4(a1, apc, aoff, 9);  mfma16(acc, a0, b0);  loadB4(b0, ub, boff, 12);
    loadA4(a0, apc, aoff, 10); mfma16(acc, a1, b1);  loadB4(b1, ub, boff, 13);
    loadA4(a1, apc, aoff, 11); mfma16(acc, a0, b2);  loadB4(b2, ub, boff, 14);
    loadA4(a0, apc, aoff, 12); mfma16(acc, a1, b3);  loadB4(b3, ub, boff, 15);
    loadA4(a1, apc, aoff, 13); mfma16(acc, a0, b0);
    loadA4(a0, apc, aoff, 14); mfma16(acc, a1, b1);
    loadA4(a1, apc, aoff, 15); mfma16(acc, a0, b2);
                               mfma16(acc, a1, b3);

    // ---------------- phase 3: epilogue ----------------
    // m = wv*32 + f*16 + c15 (f=0,1);  bit7..5 = wv, bit4 = f, bits3..0 = c15
    const float sg0 = (wv & 4) ? -1.f : 1.f;   // wire 0 <-> bit 7
    const float sg1 = (wv & 2) ? -1.f : 1.f;   // wire 1 <-> bit 6
    const float sg2 = (wv & 1) ? -1.f : 1.f;   // wire 2 <-> bit 5

#pragma unroll
    for (int rt = 0; rt < 4; ++rt) {
#pragma unroll
        for (int r = 0; r < 4; ++r) {
            const float p0 = acc[rt][0][r] * acc[rt][0][r] + acc[rt][2][r] * acc[rt][2][r];
            const float p1 = acc[rt][1][r] * acc[rt][1][r] + acc[rt][3][r] * acc[rt][3][r];
            float S = p0 + p1;
            float Sd = p0 - p1;
#pragma unroll
            for (int b = 0; b < 4; ++b) {
                float u = __shfl_xor(S, 1 << b, 64);
                S = ((c15 >> b) & 1) ? (u - S) : (S + u);
            }
#pragma unroll
            for (int b = 0; b < 4; ++b) Sd += __shfl_xor(Sd, 1 << b, 64);

            const int rowl = rt * 16 + g * 4 + r;
            if (c15 == 0) {
                zbuf[wv][rowl][0] = sg0 * S;
                zbuf[wv][rowl][1] = sg1 * S;
                zbuf[wv][rowl][2] = sg2 * S;
                zbuf[wv][rowl][3] = Sd;
            } else if (c15 == 8) {
                zbuf[wv][rowl][4] = S;
            } else if (c15 == 4) {
                zbuf[wv][rowl][5] = S;
            } else if (c15 == 2) {
                zbuf[wv][rowl][6] = S;
            } else if (c15 == 1) {
                zbuf[wv][rowl][7] = S;
            }
        }
    }
    __syncthreads();

    // ---------------- phase 4: cross-wave reduce + store ----------------
    {
        const int row = tid >> 3;
        const int i = tid & 7;
        float v = 0.f;
#pragma unroll
        for (int w2 = 0; w2 < 8; ++w2) v += zbuf[w2][row][i];
        out[(bid * 64 + row) * 8 + i] = v;
    }
}

extern "C" void kernel_launch(void* const* d_in, const int* in_sizes, int n_in,
                              void* d_out, int out_size, void* d_ws, size_t ws_size,
                              hipStream_t stream) {
    const float* x = (const float*)d_in[0];
    const float* w = (const float*)d_in[1];
    float* out = (float*)d_out;
    unsigned int* up32 = (unsigned int*)d_ws;   // 512 KB of scratch used for Upack
    const int B = in_sizes[0] / 8;
    const int nblk = B / 64;                    // 256 blocks -> 1 per CU, co-resident

    void* args[] = {(void*)&x, (void*)&w, (void*)&up32, (void*)&out};
    hipLaunchCooperativeKernel((void*)fused_kernel, dim3(nblk), dim3(512), args, 0, stream);
}

// Round 4
// 29.866 us; speedup vs baseline: 3.5250x; 3.5250x over previous
//
#include <hip/hip_runtime.h>
#include <math.h>

#define PI_F 3.14159265358979323846f

typedef _Float16 h16x8 __attribute__((ext_vector_type(8)));
typedef float f32x4 __attribute__((ext_vector_type(4)));
typedef unsigned int u32x4 __attribute__((ext_vector_type(4)));

// LDS A-tile: 16 pages (kk), page = 64 rows x 64 B, page stride padded to
// 4112 B so bank-quad rotates with kk (write lanes differ only in kk -> would
// otherwise collide on 8 banks).
#define APAGE 4112

// ---------------------------------------------------------------------------
// Register-resident 256-amp simulator (4 amps/lane, 64 lanes/wave).
// idx = lane*4 + j ; wire w acts on bit b = 7-w.
// ---------------------------------------------------------------------------

__device__ __forceinline__ void apply_ry_g(float2 a[4], const int b, const int lane,
                                           const float c, const float s) {
    if (b >= 2) {
        const int lb = b - 2;
        const float sg = ((lane >> lb) & 1) ? s : -s;
#pragma unroll
        for (int j = 0; j < 4; ++j) {
            float px = __shfl_xor(a[j].x, 1 << lb, 64);
            float py = __shfl_xor(a[j].y, 1 << lb, 64);
            a[j].x = c * a[j].x + sg * px;
            a[j].y = c * a[j].y + sg * py;
        }
    } else if (b == 1) {
        float2 n0, n1, n2, n3;
        n0.x = c * a[0].x - s * a[2].x; n0.y = c * a[0].y - s * a[2].y;
        n2.x = s * a[0].x + c * a[2].x; n2.y = s * a[0].y + c * a[2].y;
        n1.x = c * a[1].x - s * a[3].x; n1.y = c * a[1].y - s * a[3].y;
        n3.x = s * a[1].x + c * a[3].x; n3.y = s * a[1].y + c * a[3].y;
        a[0] = n0; a[1] = n1; a[2] = n2; a[3] = n3;
    } else {
        float2 n0, n1, n2, n3;
        n0.x = c * a[0].x - s * a[1].x; n0.y = c * a[0].y - s * a[1].y;
        n1.x = s * a[0].x + c * a[1].x; n1.y = s * a[0].y + c * a[1].y;
        n2.x = c * a[2].x - s * a[3].x; n2.y = c * a[2].y - s * a[3].y;
        n3.x = s * a[2].x + c * a[3].x; n3.y = s * a[2].y + c * a[3].y;
        a[0] = n0; a[1] = n1; a[2] = n2; a[3] = n3;
    }
}

__device__ __forceinline__ void apply_rx_g(float2 a[4], const int b, const int lane,
                                           const float c, const float s) {
    if (b >= 2) {
        const int lb = b - 2;
#pragma unroll
        for (int j = 0; j < 4; ++j) {
            float px = __shfl_xor(a[j].x, 1 << lb, 64);
            float py = __shfl_xor(a[j].y, 1 << lb, 64);
            a[j].x = c * a[j].x + s * py;
            a[j].y = c * a[j].y - s * px;
        }
    } else if (b == 1) {
        float2 n0, n1, n2, n3;
        n0.x = c * a[0].x + s * a[2].y; n0.y = c * a[0].y - s * a[2].x;
        n2.x = c * a[2].x + s * a[0].y; n2.y = c * a[2].y - s * a[0].x;
        n1.x = c * a[1].x + s * a[3].y; n1.y = c * a[1].y - s * a[3].x;
        n3.x = c * a[3].x + s * a[1].y; n3.y = c * a[3].y - s * a[1].x;
        a[0] = n0; a[1] = n1; a[2] = n2; a[3] = n3;
    } else {
        float2 n0, n1, n2, n3;
        n0.x = c * a[0].x + s * a[1].y; n0.y = c * a[0].y - s * a[1].x;
        n1.x = c * a[1].x + s * a[0].y; n1.y = c * a[1].y - s * a[0].x;
        n2.x = c * a[2].x + s * a[3].y; n2.y = c * a[2].y - s * a[3].x;
        n3.x = c * a[3].x + s * a[2].y; n3.y = c * a[3].y - s * a[2].x;
        a[0] = n0; a[1] = n1; a[2] = n2; a[3] = n3;
    }
}

__device__ __forceinline__ void apply_cnot_g(float2 a[4], const int cw, const int lane) {
    if (cw <= 4) {
        const int lt = (6 - cw) - 2;
        const int lc = lt + 1;
        const bool ctrl = ((lane >> lc) & 1) != 0;
#pragma unroll
        for (int j = 0; j < 4; ++j) {
            float px = __shfl_xor(a[j].x, 1 << lt, 64);
            float py = __shfl_xor(a[j].y, 1 << lt, 64);
            a[j].x = ctrl ? px : a[j].x;
            a[j].y = ctrl ? py : a[j].y;
        }
    } else if (cw == 5) {
        const bool ctrl = (lane & 1) != 0;
        float2 t;
        t = a[0]; a[0].x = ctrl ? a[2].x : a[0].x; a[0].y = ctrl ? a[2].y : a[0].y;
        a[2].x = ctrl ? t.x : a[2].x; a[2].y = ctrl ? t.y : a[2].y;
        t = a[1]; a[1].x = ctrl ? a[3].x : a[1].x; a[1].y = ctrl ? a[3].y : a[1].y;
        a[3].x = ctrl ? t.x : a[3].x; a[3].y = ctrl ? t.y : a[3].y;
    } else {
        float2 t = a[2]; a[2] = a[3]; a[3] = t;
    }
}

__device__ __forceinline__ unsigned int packh2(float lo, float hi) {
    unsigned short l = __builtin_bit_cast(unsigned short, (_Float16)lo);
    unsigned short h = __builtin_bit_cast(unsigned short, (_Float16)hi);
    return ((unsigned int)h << 16) | (unsigned int)l;
}

__device__ __forceinline__ float2 cmulf(float2 a, float2 b) {
    return make_float2(a.x * b.x - a.y * b.y, a.x * b.y + a.y * b.x);
}

// ---------------------------------------------------------------------------
// Kernel 1: build Upack (512 KB in d_ws). One block = one wave = one column.
// Global layout unchanged: f16 index = kk*16384 + c*32 + kre.
// ---------------------------------------------------------------------------
__global__ __launch_bounds__(64) void ubuild_kernel(const float* __restrict__ w,
                                                    unsigned int* __restrict__ up32) {
    __shared__ float wc[48];
    __shared__ float wsn[48];
    const int tid = threadIdx.x;
    if (tid < 48) {
        float s, c;
        __sincosf(w[tid] * 0.5f, &s, &c);
        wc[tid] = c; wsn[tid] = s;
    }
    __syncthreads();

    const int lane = tid;
    const int n = blockIdx.x;   // column 0..255

    float2 a[4];
#pragma unroll
    for (int j = 0; j < 4; ++j) {
        a[j].x = (lane * 4 + j == n) ? 1.0f : 0.0f;
        a[j].y = 0.0f;
    }

#pragma unroll
    for (int L = 0; L < 3; ++L) {
#pragma unroll
        for (int q = 0; q < 8; ++q) {
            const int k = 2 * (L * 8 + q);
            const int b = 7 - q;
            apply_rx_g(a, b, lane, wc[k], wsn[k]);
            apply_ry_g(a, b, lane, wc[k + 1], wsn[k + 1]);
        }
#pragma unroll
        for (int cwire = 0; cwire < 7; ++cwire) apply_cnot_g(a, cwire, lane);
    }

    const int kk = n >> 4;
    const int kre = 2 * (n & 15);
#pragma unroll
    for (int j = 0; j < 4; ++j) {
        const int m = lane * 4 + j;
        up32[(kk * 16384 + m * 32 + kre) >> 1] = packh2(a[j].x, -a[j].y);
        up32[(kk * 16384 + (256 + m) * 32 + kre) >> 1] = packh2(a[j].y, a[j].x);
    }
}

// ---- k-loop helpers: all-compile-time indices (no scratch) ----
__device__ __forceinline__ void loadB4(h16x8 bf[4], const char* ub, const size_t boff[4],
                                       const int kk) {
#pragma unroll
    for (int f = 0; f < 4; ++f)
        bf[f] = *(const h16x8*)(ub + (size_t)kk * 32768 + boff[f]);
}

__device__ __forceinline__ void loadA4(h16x8 av[4], const char* apc, const unsigned int aoff,
                                       const int kk) {
#pragma unroll
    for (int rt = 0; rt < 4; ++rt)
        av[rt] = *(const h16x8*)(apc + kk * APAGE + rt * 1024 + aoff);
}

__device__ __forceinline__ void mfma16(f32x4 acc[4][4], const h16x8 av[4], const h16x8 bf[4]) {
#pragma unroll
    for (int rt = 0; rt < 4; ++rt)
#pragma unroll
        for (int f = 0; f < 4; ++f)
            acc[rt][f] = __builtin_amdgcn_mfma_f32_16x16x32_f16(av[rt], bf[f], acc[rt][f],
                                                                0, 0, 0);
}

// ---------------------------------------------------------------------------
// Kernel 2: 64 samples/block. Psi tile -> swizzled LDS (b128 writes), GEMM
// with named-register depth-4 B prefetch, FWHT epilogue.
// ---------------------------------------------------------------------------
__global__ __launch_bounds__(512, 2) void gemm_kernel(const float* __restrict__ x,
                                                      const unsigned short* __restrict__ upack,
                                                      float* __restrict__ out) {
    __shared__ char Ap[16 * APAGE];               // ~64.3 KB  Apack[kk][row][64B]
    __shared__ float zbuf[8][64][8];              // 16 KB

    const int tid = threadIdx.x;

    // ---------------- phase 1: Psi tile build ----------------
    {
        const int row = tid >> 3;          // 0..63
        const int t8 = tid & 7;            // n bits 7..5
        const int grow = blockIdx.x * 64 + row;

        const float4* xp = (const float4*)(x + grow * 8);
        float4 xa = xp[0], xb = xp[1];
        float ang[8] = {xa.x, xa.y, xa.z, xa.w, xb.x, xb.y, xb.z, xb.w};

        float2 v0[8], v1[8];
#pragma unroll
        for (int i = 0; i < 8; ++i) {
            float s, c;
            __sincosf(ang[i] * (PI_F * 0.5f), &s, &c);
            v0[i] = make_float2(c * c, -c * s);
            v1[i] = make_float2(s * c, s * s);
        }

        float2 pre = (t8 & 4) ? v1[0] : v0[0];
        pre = cmulf(pre, (t8 & 2) ? v1[1] : v0[1]);
        pre = cmulf(pre, (t8 & 1) ? v1[2] : v0[2]);

        const int swz = (row >> 1) & 3;
        char* rowbase0 = Ap + row * 64;

#pragma unroll
        for (int b4 = 0; b4 < 2; ++b4) {
            float2 p3 = cmulf(pre, b4 ? v1[3] : v0[3]);
            u32x4 q0, q1, q2, q3;
#pragma unroll
            for (int b3 = 0; b3 < 2; ++b3) {
                float2 p4 = cmulf(p3, b3 ? v1[4] : v0[4]);
#pragma unroll
                for (int b2 = 0; b2 < 2; ++b2) {
                    float2 p5 = cmulf(p4, b2 ? v1[5] : v0[5]);
#pragma unroll
                    for (int b1 = 0; b1 < 2; ++b1) {
                        float2 p6 = cmulf(p5, b1 ? v1[6] : v0[6]);
#pragma unroll
                        for (int b0 = 0; b0 < 2; ++b0) {
                            float2 ps = cmulf(p6, b0 ? v1[7] : v0[7]);
                            const int i4 = (b3 << 3) | (b2 << 2) | (b1 << 1) | b0;
                            const unsigned int val = packh2(ps.x, ps.y);
                            const int ch = i4 >> 2, pos = i4 & 3;
                            if (ch == 0) q0[pos] = val;
                            else if (ch == 1) q1[pos] = val;
                            else if (ch == 2) q2[pos] = val;
                            else q3[pos] = val;
                        }
                    }
                }
            }
            const int kk = t8 * 2 + b4;
            char* base = rowbase0 + kk * APAGE;
            *(u32x4*)(base + (0 ^ swz) * 16) = q0;
            *(u32x4*)(base + (1 ^ swz) * 16) = q1;
            *(u32x4*)(base + (2 ^ swz) * 16) = q2;
            *(u32x4*)(base + (3 ^ swz) * 16) = q3;
        }
    }
    __syncthreads();

    // ---------------- phase 2: GEMM ----------------
    const int lane = tid & 63;
    const int wv = tid >> 6;        // 0..7 : re cols [wv*32, wv*32+32)
    const int c15 = lane & 15;
    const int g = lane >> 4;

    const char* ub = (const char*)upack;
    size_t boff[4];
    {
        const int cb0 = wv * 32;
        boff[0] = (size_t)(cb0 + c15) * 64 + g * 16;
        boff[1] = (size_t)(cb0 + 16 + c15) * 64 + g * 16;
        boff[2] = (size_t)(256 + cb0 + c15) * 64 + g * 16;
        boff[3] = (size_t)(256 + cb0 + 16 + c15) * 64 + g * 16;
    }
    const unsigned int aoff = c15 * 64 + ((g ^ ((c15 >> 1) & 3)) * 16);
    const char* apc = (const char*)Ap;

    f32x4 acc[4][4];
#pragma unroll
    for (int rt = 0; rt < 4; ++rt)
#pragma unroll
        for (int f = 0; f < 4; ++f) {
            f32x4 z = {0.f, 0.f, 0.f, 0.f};
            acc[rt][f] = z;
        }

    h16x8 b0[4], b1[4], b2[4], b3[4];
    h16x8 a0[4], a1[4];

    loadB4(b0, ub, boff, 0);
    loadB4(b1, ub, boff, 1);
    loadB4(b2, ub, boff, 2);
    loadB4(b3, ub, boff, 3);
    loadA4(a0, apc, aoff, 0);

    loadA4(a1, apc, aoff, 1);  mfma16(acc, a0, b0);  loadB4(b0, ub, boff, 4);
    loadA4(a0, apc, aoff, 2);  mfma16(acc, a1, b1);  loadB4(b1, ub, boff, 5);
    loadA4(a1, apc, aoff, 3);  mfma16(acc, a0, b2);  loadB4(b2, ub, boff, 6);
    loadA4(a0, apc, aoff, 4);  mfma16(acc, a1, b3);  loadB4(b3, ub, boff, 7);
    loadA4(a1, apc, aoff, 5);  mfma16(acc, a0, b0);  loadB4(b0, ub, boff, 8);
    loadA4(a0, apc, aoff, 6);  mfma16(acc, a1, b1);  loadB4(b1, ub, boff, 9);
    loadA4(a1, apc, aoff, 7);  mfma16(acc, a0, b2);  loadB4(b2, ub, boff, 10);
    loadA4(a0, apc, aoff, 8);  mfma16(acc, a1, b3);  loadB4(b3, ub, boff, 11);
    loadA4(a1, apc, aoff, 9);  mfma16(acc, a0, b0);  loadB4(b0, ub, boff, 12);
    loadA4(a0, apc, aoff, 10); mfma16(acc, a1, b1);  loadB4(b1, ub, boff, 13);
    loadA4(a1, apc, aoff, 11); mfma16(acc, a0, b2);  loadB4(b2, ub, boff, 14);
    loadA4(a0, apc, aoff, 12); mfma16(acc, a1, b3);  loadB4(b3, ub, boff, 15);
    loadA4(a1, apc, aoff, 13); mfma16(acc, a0, b0);
    loadA4(a0, apc, aoff, 14); mfma16(acc, a1, b1);
    loadA4(a1, apc, aoff, 15); mfma16(acc, a0, b2);
                               mfma16(acc, a1, b3);

    // ---------------- phase 3: epilogue ----------------
    // m = wv*32 + f*16 + c15 (f=0,1);  bit7..5 = wv, bit4 = f, bits3..0 = c15
    const float sg0 = (wv & 4) ? -1.f : 1.f;
    const float sg1 = (wv & 2) ? -1.f : 1.f;
    const float sg2 = (wv & 1) ? -1.f : 1.f;

#pragma unroll
    for (int rt = 0; rt < 4; ++rt) {
#pragma unroll
        for (int r = 0; r < 4; ++r) {
            const float p0 = acc[rt][0][r] * acc[rt][0][r] + acc[rt][2][r] * acc[rt][2][r];
            const float p1 = acc[rt][1][r] * acc[rt][1][r] + acc[rt][3][r] * acc[rt][3][r];
            float S = p0 + p1;
            float Sd = p0 - p1;
#pragma unroll
            for (int b = 0; b < 4; ++b) {
                float u = __shfl_xor(S, 1 << b, 64);
                S = ((c15 >> b) & 1) ? (u - S) : (S + u);
            }
#pragma unroll
            for (int b = 0; b < 4; ++b) Sd += __shfl_xor(Sd, 1 << b, 64);

            const int rowl = rt * 16 + g * 4 + r;
            if (c15 == 0) {
                zbuf[wv][rowl][0] = sg0 * S;
                zbuf[wv][rowl][1] = sg1 * S;
                zbuf[wv][rowl][2] = sg2 * S;
                zbuf[wv][rowl][3] = Sd;
            } else if (c15 == 8) {
                zbuf[wv][rowl][4] = S;
            } else if (c15 == 4) {
                zbuf[wv][rowl][5] = S;
            } else if (c15 == 2) {
                zbuf[wv][rowl][6] = S;
            } else if (c15 == 1) {
                zbuf[wv][rowl][7] = S;
            }
        }
    }
    __syncthreads();

    // ---------------- phase 4: cross-wave reduce + store ----------------
    {
        const int row = tid >> 3;
        const int i = tid & 7;
        float v = 0.f;
#pragma unroll
        for (int w2 = 0; w2 < 8; ++w2) v += zbuf[w2][row][i];
        out[(blockIdx.x * 64 + row) * 8 + i] = v;
    }
}

extern "C" void kernel_launch(void* const* d_in, const int* in_sizes, int n_in,
                              void* d_out, int out_size, void* d_ws, size_t ws_size,
                              hipStream_t stream) {
    const float* x = (const float*)d_in[0];
    const float* w = (const float*)d_in[1];
    float* out = (float*)d_out;
    const int B = in_sizes[0] / 8;

    unsigned int* up32 = (unsigned int*)d_ws;           // 512 KB used
    ubuild_kernel<<<256, 64, 0, stream>>>(w, up32);

    const unsigned short* upack = (const unsigned short*)d_ws;
    gemm_kernel<<<B / 64, 512, 0, stream>>>(x, upack, out);
}